// Round 20
// baseline (95.882 us; speedup 1.0000x reference)
//
#include <hip/hip_runtime.h>
#include <stdint.h>

// Problem constants
#define B_   2
#define S_   2048
#define HID  1024
#define NH   16
#define CH   64
#define MTOT (B_ * S_)          // 4096 rows
#define NELEM ((size_t)MTOT * HID)   // 4,194,304 per matrix
#define WELEM ((size_t)HID * HID)    // 1,048,576 per weight

typedef unsigned short u16;
typedef unsigned int u32;
typedef __attribute__((ext_vector_type(4))) float f32x4;
typedef __attribute__((ext_vector_type(8))) short s16x8;
typedef __attribute__((ext_vector_type(4))) short s16x4;

// ---------- helpers ----------
__device__ __forceinline__ u16 f2bf(float f) {
  union { float f; unsigned u; } v; v.f = f;
  unsigned u = v.u;
  return (u16)((u + 0x7FFFu + ((u >> 16) & 1u)) >> 16);  // RNE (R3/R4-verified)
}

__device__ __forceinline__ float bf2f(u16 h) {
  union { unsigned u; float f; } v; v.u = ((u32)h) << 16; return v.f;
}

// Raw v_exp_f32 (2^x) — R19-verified vs guarded exp2f libcall.
__device__ __forceinline__ float fexp2(float x) {
  float r; asm("v_exp_f32 %0, %1" : "=v"(r) : "v"(x)); return r;
}

__device__ __forceinline__ f32x4 mfma16(s16x8 a, s16x8 b, f32x4 c) {
  // v_mfma_f32_16x16x32_bf16 (m89-verified layouts). GEMM-only (18 rounds clean).
  asm("v_mfma_f32_16x16x32_bf16 %0, %1, %2, %0" : "+v"(c) : "v"(a), "v"(b));
  return c;
}

// D != C form: SrcC is a separate (persistent, never-rewritten) register.
__device__ __forceinline__ f32x4 mfma16z(s16x8 a, s16x8 b, f32x4 c) {
  f32x4 d;
  asm("v_mfma_f32_16x16x32_bf16 %0, %1, %2, %3"
      : "=&v"(d) : "v"(a), "v"(b), "v"(c));
  return d;
}

// Tied same-register accumulate (HW-interlocked MFMA->MFMA same-acc chain).
__device__ __forceinline__ f32x4 mfma16t(s16x8 a, s16x8 b, f32x4 c) {
  asm("v_mfma_f32_16x16x32_bf16 %0, %1, %2, %0" : "+&v"(c) : "v"(a), "v"(b));
  return c;
}

// 16x16x16 bf16, tied accumulate (o[n] regs only ever written by MFMA in-loop).
__device__ __forceinline__ f32x4 mfma16k16t(s16x4 a, s16x4 b, f32x4 c) {
  asm("v_mfma_f32_16x16x16_bf16 %0, %1, %2, %0" : "+&v"(c) : "v"(a), "v"(b));
  return c;
}

__device__ __forceinline__ u32 cvtpk(float lo, float hi) {
  u32 r;
  asm("v_cvt_pk_bf16_f32 %0, %1, %2" : "=v"(r) : "v"(lo), "v"(hi));
  return r;
}

// 24-cycle fence before VALU reads of MFMA D results.
__device__ __forceinline__ void mfma_fence() {
  asm volatile("s_nop 7\n\ts_nop 7\n\ts_nop 7" ::: );
}

__device__ __forceinline__ void gload_lds16(const u16* g, u16* l) {
  __builtin_amdgcn_global_load_lds((const __attribute__((address_space(1))) void*)g,
                                   (__attribute__((address_space(3))) void*)l,
                                   16, 0, 0);
}

// ---------- kernel 1: W (fp32 [K][N]) -> W^T (bf16 [N][K]) ----------
__global__ __launch_bounds__(256) void k_transposeW(const float* __restrict__ w0,
                                                    const float* __restrict__ w1,
                                                    const float* __restrict__ w2,
                                                    u16* __restrict__ wT) {
  const float* w = (blockIdx.z == 0) ? w0 : (blockIdx.z == 1) ? w1 : w2;
  u16* o = wT + (size_t)blockIdx.z * WELEM;
  __shared__ u16 tile[64][65];
  int x = threadIdx.x & 63, y = threadIdx.x >> 6;
  int r0 = blockIdx.x * 64, c0 = blockIdx.y * 64;
#pragma unroll
  for (int i = 0; i < 16; ++i) {
    int r = i * 4 + y;
    tile[r][x] = f2bf(w[(size_t)(r0 + r) * HID + c0 + x]);
  }
  __syncthreads();
#pragma unroll
  for (int i = 0; i < 16; ++i) {
    int cc = i * 4 + y;
    o[(size_t)(c0 + cc) * HID + r0 + x] = tile[x][cc];
  }
}

// ---------- kernel 2: FUSED bf16 GEMM (R17-exact: depth-1, swizzled) ----------
// C = cvt_bf16(Afp32) @ BT^T. 2x LDS buffers; per K-step: barrier -> issue
// next B gload_lds + next A fp32 loads -> 16 MFMA -> cvt + ds_write next A.
// 16B-slot XOR swizzle (conflicts = 0, R16-verified). XCD panel-chunk (R14).
__global__ __launch_bounds__(256) void k_gemm(const float* __restrict__ qf32,
                                              const float* __restrict__ kf32,
                                              const float* __restrict__ vf32,
                                              const u16* __restrict__ BTall,
                                              u16* __restrict__ Call,
                                              u16* __restrict__ Vfrag) {
  int lin = blockIdx.x;                  // 0..767
  int xcd = lin & 7;
  int chunk = xcd * 96 + (lin >> 3);     // contiguous 96-chunk per XCD (R14)
  int zz = chunk >> 8;
  int rem = chunk & 255;
  int ty = rem >> 3;                     // row-tile 0..31 (A panel)
  int tx = rem & 7;                      // col-tile 0..7

  const float* Af = (zz == 0) ? qf32 : (zz == 1) ? kf32 : vf32;
  const u16* BT = BTall + (size_t)zz * WELEM;
  u16*       C  = Call  + (size_t)zz * NELEM;
  int row0 = ty * 128, col0 = tx * 128;

  __shared__ __align__(16) u16 sA[2][128 * 32];
  __shared__ __align__(16) u16 sB[2][128 * 32];

  int t = threadIdx.x;
  int wave = t >> 6, lane = t & 63;
  int lrow = lane & 15, lhi = lane >> 4;
  int wr = wave >> 1, wc = wave & 1;

  f32x4 acc[4][4] = {};
  int kswz = (lhi ^ ((lrow >> 1) & 3)) << 3;   // read-side swizzle (invariant)

#define STAGE_B(KT, BUF)                                                       \
  _Pragma("unroll")                                                            \
  for (int r = 0; r < 2; ++r) {                                                \
    int idx = r * 256 + t;                                                     \
    int srow = idx >> 2;                                                       \
    int scol = (((idx & 3) ^ ((srow >> 1) & 3)) << 3);                         \
    int ldsoff = (r * 256 + wave * 64) * 8;                                    \
    gload_lds16(BT + (size_t)(col0 + srow) * HID + (KT) + scol,                \
                &sB[BUF][0] + ldsoff);                                         \
  }

#define LOAD_A(KT)                                                             \
  _Pragma("unroll")                                                            \
  for (int r = 0; r < 2; ++r) {                                                \
    int idx = r * 256 + t;                                                     \
    const float* ap = Af + (size_t)(row0 + (idx >> 2)) * HID + (KT) +          \
                      ((idx & 3) << 3);                                        \
    areg0[r] = *(const f32x4*)ap;                                              \
    areg1[r] = *(const f32x4*)(ap + 4);                                        \
  }

#define WRITE_A(BUF)                                                           \
  _Pragma("unroll")                                                            \
  for (int r = 0; r < 2; ++r) {                                                \
    int idx = r * 256 + t;                                                     \
    int srow = idx >> 2;                                                       \
    int slot = (idx & 3) ^ ((srow >> 1) & 3);                                  \
    union { u32 u[4]; s16x8 v; } aw;                                           \
    aw.u[0] = cvtpk(areg0[r][0], areg0[r][1]);                                 \
    aw.u[1] = cvtpk(areg0[r][2], areg0[r][3]);                                 \
    aw.u[2] = cvtpk(areg1[r][0], areg1[r][1]);                                 \
    aw.u[3] = cvtpk(areg1[r][2], areg1[r][3]);                                 \
    *(s16x8*)&sA[BUF][srow * 32 + slot * 8] = aw.v;                            \
  }

  f32x4 areg0[2], areg1[2];
  STAGE_B(0, 0);
  LOAD_A(0);
  WRITE_A(0);

  for (int kt = 0; kt < HID; kt += 32) {
    int cur = (kt >> 5) & 1;
    __syncthreads();
    bool more = (kt + 32) < HID;
    if (more) {
      STAGE_B(kt + 32, 1 - cur);
      LOAD_A(kt + 32);
    }
    s16x8 af[4], bfr[4];
#pragma unroll
    for (int m = 0; m < 4; ++m)
      af[m] = *(const s16x8*)&sA[cur][(wr * 64 + m * 16 + lrow) * 32 + kswz];
#pragma unroll
    for (int n = 0; n < 4; ++n)
      bfr[n] = *(const s16x8*)&sB[cur][(wc * 64 + n * 16 + lrow) * 32 + kswz];
#pragma unroll
    for (int m = 0; m < 4; ++m)
#pragma unroll
      for (int n = 0; n < 4; ++n)
        acc[m][n] = mfma16(af[m], bfr[n], acc[m][n]);
    if (more) {
      WRITE_A(1 - cur);
    }
  }
#undef STAGE_B
#undef LOAD_A
#undef WRITE_A
  mfma_fence();
  if (zz == 2) {
    // packed V-frag epilogue (R9-verified)
#pragma unroll
    for (int m = 0; m < 4; ++m)
#pragma unroll
      for (int n = 0; n < 4; ++n) {
        int rr = row0 + wr * 64 + m * 16 + lhi * 4;       // t-row of j=0
        int cc = col0 + wc * 64 + n * 16 + lrow;          // hidden col
        int bb = rr >> 11, tt = rr & 2047;
        int hh = cc >> 6, chl = cc & 63;
        size_t off = ((size_t)(bb * NH + hh)) * ((size_t)CH * S_) +
                     (size_t)(((tt >> 4) * 4 + (chl >> 4)) * 256 +
                              ((tt >> 2) & 3) * 64 + (chl & 15) * 4);
        u32 w0 = (u32)f2bf(acc[m][n][0]) | ((u32)f2bf(acc[m][n][1]) << 16);
        u32 w1 = (u32)f2bf(acc[m][n][2]) | ((u32)f2bf(acc[m][n][3]) << 16);
        uint2 w; w.x = w0; w.y = w1;
        *(uint2*)&Vfrag[off] = w;
      }
  } else {
    // z==0: fold 1/sqrt(64) AND 1/ln(2) so k_attn uses exp2 directly
    float scl = (zz == 0) ? 0.125f * 1.44269504f : 1.0f;
#pragma unroll
    for (int m = 0; m < 4; ++m)
#pragma unroll
      for (int n = 0; n < 4; ++n)
#pragma unroll
        for (int j = 0; j < 4; ++j) {
          int rr = row0 + wr * 64 + m * 16 + lhi * 4 + j;
          int cc = col0 + wc * 64 + n * 16 + lrow;
          C[(size_t)rr * HID + cc] = f2bf(acc[m][n][j] * scl);
        }
  }
}

// ---------- kernel 3: causal flash attention, KV-SPLIT bf16 partials ----------
// R19-verified core. R20: V-frags read DIRECTLY from global (L2/L1) -- all 32
// blocks of a bh land on one XCD (linear=yy*32+bh, xcd=bh&7) so the 256KB
// V-frag region is L2-hot, and all 8 waves read the same 8KB tile (L1-served).
// Deletes V staging: LDS 32KB->16KB, LDS-pipe per wave-step halved, barrier
// drain no longer couples V. K staging unchanged (uncoalesced from global).
__global__ __launch_bounds__(512) void k_attn(const u16* __restrict__ eq,
                                              const u16* __restrict__ ek,
                                              const u16* __restrict__ vf,
                                              u16* __restrict__ op0,
                                              u16* __restrict__ op1,
                                              float* __restrict__ lp) {
  int bh = blockIdx.x;                 // b*NH + h
  int b = bh >> 4, h = bh & 15;
  int yy = blockIdx.y;                 // heavy-first: qt = 15 - (yy>>1)
  int qt = 15 - (yy >> 1);
  int half = yy & 1;
  int q0b = qt * 128;
  int wave = threadIdx.x >> 6, lane = threadIdx.x & 63;
  int lrow = lane & 15, lhi = lane >> 4;
  int q0w = q0b + wave * 16;

  // flattened LDS: [0,4096) K buf0 | [4096,8192) K buf1   (u16 units)
  __shared__ __align__(16) u16 sKV[8192];

  const u16* gK = ek + (size_t)(b * S_) * HID + h * CH;
  const u16* gV = vf + (size_t)bh * ((size_t)CH * S_);

  // Q fragments (emb_q pre-scaled); swapped-QK B-frag layout.
  s16x8 qf[2];
  {
    size_t qbase = (size_t)(b * S_ + q0w + lrow) * HID + h * CH;
    qf[0] = *(const s16x8*)(eq + qbase + lhi * 8);
    qf[1] = *(const s16x8*)(eq + qbase + 32 + lhi * 8);
  }

  f32x4 o[4] = {};                 // accumulated ONLY by MFMA inside the loop
  f32x4 zreg = {0.f, 0.f, 0.f, 0.f};   // persistent SrcC zero (never rewritten)
  float lsum = 0.0f;

  // K staging lane mapping (XOR-swizzled; chunk = 8 t-rows; wave stages chunk w)
  int lr8 = lane >> 3, slot = lane & 7;
  int co = ((slot ^ lr8) << 3);    // inverse-swizzled source column (elems)

  // loop-invariant lane read bases (u16 units)
  int kb_lane = lrow * 64 + ((lhi ^ (lrow & 7)) << 3);   // K frag base (1st half)
  int vb_lane = lhi * 64 + lrow * 4;                     // V frag base (global)

  int nst = qt + 1;                // steps in this half
  int sbase = half * nst;          // global step offset
  int tb0 = sbase * 64;

  // prologue: stage first K tile of this half into buf0
  gload_lds16(gK + (size_t)(tb0 + wave * 8 + lr8) * HID + co, &sKV[wave * 512]);

#define ATTN_STEP(ST, BUF)                                                     \
  {                                                                            \
    int tb = (sbase + (ST)) * 64;                                              \
    __syncthreads();                                                           \
    if ((ST) + 1 < nst) {                                                      \
      int tb2 = tb + 64;                                                       \
      gload_lds16(gK + (size_t)(tb2 + wave * 8 + lr8) * HID + co,              \
                  &sKV[(1 - (BUF)) * 4096 + wave * 512]);                      \
    }                                                                          \
    if (tb <= q0w + 15) {                                                      \
      const u16* vt = gV + (size_t)(sbase + (ST)) * 4096 + vb_lane;            \
      f32x4 p[4];                                                              \
      _Pragma("unroll")                                                        \
      for (int kvf = 0; kvf < 4; ++kvf) {                                      \
        s16x8 k0 = *(const s16x8*)&sKV[(BUF) * 4096 + kvf * 1024 + kb_lane];   \
        s16x8 k1 = *(const s16x8*)&sKV[(BUF) * 4096 + kvf * 1024 +             \
                                       (kb_lane ^ 32)];                        \
        p[kvf] = mfma16z(k0, qf[0], zreg);                                     \
        p[kvf] = mfma16t(k1, qf[1], p[kvf]);                                   \
      }                                                                        \
      mfma_fence();                                                            \
      s16x4 pa[4];                                                             \
      if (tb + 63 > q0w) {            /* diagonal step: wave-uniform branch */ \
        _Pragma("unroll")                                                      \
        for (int kvf = 0; kvf < 4; ++kvf) {                                    \
          float e[4];                                                          \
          _Pragma("unroll")                                                    \
          for (int j = 0; j < 4; ++j) {                                        \
            float v = p[kvf][j];                                               \
            if (tb + kvf * 16 + lhi * 4 + j > q0w + lrow) v = -3.0e38f;        \
            e[j] = fexp2(v);                                                   \
          }                                                                    \
          lsum += (e[0] + e[1]) + (e[2] + e[3]);                               \
          union { u32 u[2]; s16x4 v4; } pk;                                    \
          pk.u[0] = cvtpk(e[0], e[1]);                                         \
          pk.u[1] = cvtpk(e[2], e[3]);                                         \
          pa[kvf] = pk.v4;                                                     \
        }                                                                      \
      } else {                        /* interior step: no mask VALU at all */ \
        _Pragma("unroll")                                                      \
        for (int kvf = 0; kvf < 4; ++kvf) {                                    \
          float e[4];                                                          \
          _Pragma("unroll")                                                    \
          for (int j = 0; j < 4; ++j) e[j] = fexp2(p[kvf][j]);                 \
          lsum += (e[0] + e[1]) + (e[2] + e[3]);                               \
          union { u32 u[2]; s16x4 v4; } pk;                                    \
          pk.u[0] = cvtpk(e[0], e[1]);                                         \
          pk.u[1] = cvtpk(e[2], e[3]);                                         \
          pa[kvf] = pk.v4;                                                     \
        }                                                                      \
      }                                                                        \
      asm volatile("s_nop 1" :::);  /* cvtpk(VALU) -> pa as MFMA SrcA guard */ \
      _Pragma("unroll")                                                        \
      for (int n = 0; n < 4; ++n)                                              \
        _Pragma("unroll")                                                      \
        for (int kvf = 0; kvf < 4; ++kvf) {                                    \
          s16x4 vfr = *(const s16x4*)&vt[(kvf * 4 + n) * 256];                 \
          o[n] = mfma16k16t(pa[kvf], vfr, o[n]);                               \
        }                                                                      \
    }                                                                          \
  }

  for (int st2 = 0; st2 < nst; st2 += 2) {
    ATTN_STEP(st2, 0);
    if (st2 + 1 < nst) ATTN_STEP(st2 + 1, 1);
  }
#undef ATTN_STEP

  mfma_fence();

  // reduce lsum across the 4 hi-groups: every lane ends with total for q = lrow
  lsum += __shfl_xor(lsum, 16);
  lsum += __shfl_xor(lsum, 32);

  u16* ob = half ? op1 : op0;
#pragma unroll
  for (int j = 0; j < 4; ++j) {
    int q = q0w + lhi * 4 + j;
    u16* op = ob + (size_t)(b * S_ + q) * HID + h * CH + lrow;
#pragma unroll
    for (int n = 0; n < 4; ++n)
      op[n * 16] = f2bf(o[n][j]);        // unnormalized bf16 partial
  }
  if (lhi == 0) {                        // one lane set per q-row
    int q = q0w + lrow;
    lp[(((size_t)half * B_ + b) * S_ + q) * NH + h] = lsum;
  }
}

// ---------- kernel 4: combine bf16 partials + normalize -> fp32 out ----------
__global__ __launch_bounds__(256) void k_combine(float* __restrict__ out,
                                                 const u16* __restrict__ p0,
                                                 const u16* __restrict__ p1,
                                                 const float* __restrict__ lp) {
  size_t i = ((size_t)blockIdx.x * 256 + threadIdx.x) * 8;
  size_t row = i >> 10;                  // b*S + s
  int h = (int)((i & 1023) >> 6);        // same h for all 8
  size_t b = row >> 11, s = row & 2047;
  float l0 = lp[((0 * B_ + b) * S_ + s) * NH + h];
  float l1 = lp[((1 * B_ + b) * S_ + s) * NH + h];
  float inv = 1.0f / (l0 + l1);
  uint4 a = *(const uint4*)&p0[i];
  uint4 c = *(const uint4*)&p1[i];
  f32x4 r0, r1;
  r0[0] = (bf2f((u16)(a.x & 0xFFFF)) + bf2f((u16)(c.x & 0xFFFF))) * inv;
  r0[1] = (bf2f((u16)(a.x >> 16))    + bf2f((u16)(c.x >> 16)))    * inv;
  r0[2] = (bf2f((u16)(a.y & 0xFFFF)) + bf2f((u16)(c.y & 0xFFFF))) * inv;
  r0[3] = (bf2f((u16)(a.y >> 16))    + bf2f((u16)(c.y >> 16)))    * inv;
  r1[0] = (bf2f((u16)(a.z & 0xFFFF)) + bf2f((u16)(c.z & 0xFFFF))) * inv;
  r1[1] = (bf2f((u16)(a.z >> 16))    + bf2f((u16)(c.z >> 16)))    * inv;
  r1[2] = (bf2f((u16)(a.w & 0xFFFF)) + bf2f((u16)(c.w & 0xFFFF))) * inv;
  r1[3] = (bf2f((u16)(a.w >> 16))    + bf2f((u16)(c.w >> 16)))    * inv;
  *(f32x4*)(out + i) = r0;
  *(f32x4*)(out + i + 4) = r1;
}

// ---------- launch ----------
extern "C" void kernel_launch(void* const* d_in, const int* in_sizes, int n_in,
                              void* d_out, int out_size, void* d_ws, size_t ws_size,
                              hipStream_t stream) {
  const float* q  = (const float*)d_in[0];
  const float* k  = (const float*)d_in[1];
  const float* v  = (const float*)d_in[2];
  const float* wq = (const float*)d_in[3];
  const float* wk = (const float*)d_in[4];
  const float* wv = (const float*)d_in[5];
  float* out = (float*)d_out;

  // layout: first 24MB region is scratch for partials; rest unchanged.
  u16* scratch = (u16*)d_ws;             // 3*NELEM u16 region
  u16* wT  = scratch + 3 * NELEM;        // 3 * WELEM
  u16* emb = wT + 3 * WELEM;             // 3 * NELEM (z2 slot holds V-frag)
  u16* vfr = emb + 2 * NELEM;            // packed V-frag written by k_gemm z==2

  u16* p0b = scratch;                    // NELEM bf16 = 8 MB
  u16* p1b = scratch + NELEM;            // NELEM bf16 = 8 MB
  float* lp = (float*)(scratch + 2 * NELEM);  // 2*B*S*NH fp32 = 512 KB

  k_transposeW<<<dim3(16, 16, 3), 256, 0, stream>>>(wq, wk, wv, wT);
  k_gemm<<<dim3(768), 256, 0, stream>>>(q, k, v, wT, emb, vfr);
  k_attn<<<dim3(B_ * NH, 32), 512, 0, stream>>>(emb, emb + NELEM, vfr,
                                                p0b, p1b, lp);
  k_combine<<<dim3(NELEM / (256 * 8)), 256, 0, stream>>>(out, p0b, p1b, lp);
}

// Round 21
// 79.920 us; speedup vs baseline: 1.1997x; 1.1997x over previous
//
#include <hip/hip_runtime.h>
#include <stdint.h>

// Problem constants
#define B_   2
#define S_   2048
#define HID  1024
#define NH   16
#define CH   64
#define MTOT (B_ * S_)          // 4096 rows
#define NELEM ((size_t)MTOT * HID)   // 4,194,304 per matrix
#define WELEM ((size_t)HID * HID)    // 1,048,576 per weight

typedef unsigned short u16;
typedef unsigned int u32;
typedef __attribute__((ext_vector_type(4))) float f32x4;
typedef __attribute__((ext_vector_type(8))) short s16x8;
typedef __attribute__((ext_vector_type(4))) short s16x4;

// ---------- helpers ----------
__device__ __forceinline__ u16 f2bf(float f) {
  union { float f; unsigned u; } v; v.f = f;
  unsigned u = v.u;
  return (u16)((u + 0x7FFFu + ((u >> 16) & 1u)) >> 16);  // RNE (R3/R4-verified)
}

__device__ __forceinline__ float bf2f(u16 h) {
  union { unsigned u; float f; } v; v.u = ((u32)h) << 16; return v.f;
}

// Raw v_exp_f32 (2^x) — R19-verified vs guarded exp2f libcall.
__device__ __forceinline__ float fexp2(float x) {
  float r; asm("v_exp_f32 %0, %1" : "=v"(r) : "v"(x)); return r;
}

__device__ __forceinline__ f32x4 mfma16(s16x8 a, s16x8 b, f32x4 c) {
  // v_mfma_f32_16x16x32_bf16 (m89-verified layouts). GEMM-only (19 rounds clean).
  asm("v_mfma_f32_16x16x32_bf16 %0, %1, %2, %0" : "+v"(c) : "v"(a), "v"(b));
  return c;
}

// D != C form: SrcC is a separate (persistent, never-rewritten) register.
__device__ __forceinline__ f32x4 mfma16z(s16x8 a, s16x8 b, f32x4 c) {
  f32x4 d;
  asm("v_mfma_f32_16x16x32_bf16 %0, %1, %2, %3"
      : "=&v"(d) : "v"(a), "v"(b), "v"(c));
  return d;
}

// Tied same-register accumulate (HW-interlocked MFMA->MFMA same-acc chain).
__device__ __forceinline__ f32x4 mfma16t(s16x8 a, s16x8 b, f32x4 c) {
  asm("v_mfma_f32_16x16x32_bf16 %0, %1, %2, %0" : "+&v"(c) : "v"(a), "v"(b));
  return c;
}

// 16x16x16 bf16, tied accumulate (o[n] regs only ever written by MFMA in-loop).
__device__ __forceinline__ f32x4 mfma16k16t(s16x4 a, s16x4 b, f32x4 c) {
  asm("v_mfma_f32_16x16x16_bf16 %0, %1, %2, %0" : "+&v"(c) : "v"(a), "v"(b));
  return c;
}

__device__ __forceinline__ u32 cvtpk(float lo, float hi) {
  u32 r;
  asm("v_cvt_pk_bf16_f32 %0, %1, %2" : "=v"(r) : "v"(lo), "v"(hi));
  return r;
}

// 24-cycle fence before VALU reads of MFMA D results.
__device__ __forceinline__ void mfma_fence() {
  asm volatile("s_nop 7\n\ts_nop 7\n\ts_nop 7" ::: );
}

__device__ __forceinline__ void gload_lds16(const u16* g, u16* l) {
  __builtin_amdgcn_global_load_lds((const __attribute__((address_space(1))) void*)g,
                                   (__attribute__((address_space(3))) void*)l,
                                   16, 0, 0);
}

// ---------- kernel 1: W (fp32 [K][N]) -> W^T (bf16 [N][K]) ----------
__global__ __launch_bounds__(256) void k_transposeW(const float* __restrict__ w0,
                                                    const float* __restrict__ w1,
                                                    const float* __restrict__ w2,
                                                    u16* __restrict__ wT) {
  const float* w = (blockIdx.z == 0) ? w0 : (blockIdx.z == 1) ? w1 : w2;
  u16* o = wT + (size_t)blockIdx.z * WELEM;
  __shared__ u16 tile[64][65];
  int x = threadIdx.x & 63, y = threadIdx.x >> 6;
  int r0 = blockIdx.x * 64, c0 = blockIdx.y * 64;
#pragma unroll
  for (int i = 0; i < 16; ++i) {
    int r = i * 4 + y;
    tile[r][x] = f2bf(w[(size_t)(r0 + r) * HID + c0 + x]);
  }
  __syncthreads();
#pragma unroll
  for (int i = 0; i < 16; ++i) {
    int cc = i * 4 + y;
    o[(size_t)(c0 + cc) * HID + r0 + x] = tile[x][cc];
  }
}

// ---------- kernel 2: FUSED bf16 GEMM (R17-exact: depth-1, swizzled) ----------
// C = cvt_bf16(Afp32) @ BT^T. 2x LDS buffers; per K-step: barrier -> issue
// next B gload_lds + next A fp32 loads -> 16 MFMA -> cvt + ds_write next A.
// 16B-slot XOR swizzle (conflicts = 0, R16-verified). XCD panel-chunk (R14).
__global__ __launch_bounds__(256) void k_gemm(const float* __restrict__ qf32,
                                              const float* __restrict__ kf32,
                                              const float* __restrict__ vf32,
                                              const u16* __restrict__ BTall,
                                              u16* __restrict__ Call,
                                              u16* __restrict__ Vfrag) {
  int lin = blockIdx.x;                  // 0..767
  int xcd = lin & 7;
  int chunk = xcd * 96 + (lin >> 3);     // contiguous 96-chunk per XCD (R14)
  int zz = chunk >> 8;
  int rem = chunk & 255;
  int ty = rem >> 3;                     // row-tile 0..31 (A panel)
  int tx = rem & 7;                      // col-tile 0..7

  const float* Af = (zz == 0) ? qf32 : (zz == 1) ? kf32 : vf32;
  const u16* BT = BTall + (size_t)zz * WELEM;
  u16*       C  = Call  + (size_t)zz * NELEM;
  int row0 = ty * 128, col0 = tx * 128;

  __shared__ __align__(16) u16 sA[2][128 * 32];
  __shared__ __align__(16) u16 sB[2][128 * 32];

  int t = threadIdx.x;
  int wave = t >> 6, lane = t & 63;
  int lrow = lane & 15, lhi = lane >> 4;
  int wr = wave >> 1, wc = wave & 1;

  f32x4 acc[4][4] = {};
  int kswz = (lhi ^ ((lrow >> 1) & 3)) << 3;   // read-side swizzle (invariant)

#define STAGE_B(KT, BUF)                                                       \
  _Pragma("unroll")                                                            \
  for (int r = 0; r < 2; ++r) {                                                \
    int idx = r * 256 + t;                                                     \
    int srow = idx >> 2;                                                       \
    int scol = (((idx & 3) ^ ((srow >> 1) & 3)) << 3);                         \
    int ldsoff = (r * 256 + wave * 64) * 8;                                    \
    gload_lds16(BT + (size_t)(col0 + srow) * HID + (KT) + scol,                \
                &sB[BUF][0] + ldsoff);                                         \
  }

#define LOAD_A(KT)                                                             \
  _Pragma("unroll")                                                            \
  for (int r = 0; r < 2; ++r) {                                                \
    int idx = r * 256 + t;                                                     \
    const float* ap = Af + (size_t)(row0 + (idx >> 2)) * HID + (KT) +          \
                      ((idx & 3) << 3);                                        \
    areg0[r] = *(const f32x4*)ap;                                              \
    areg1[r] = *(const f32x4*)(ap + 4);                                        \
  }

#define WRITE_A(BUF)                                                           \
  _Pragma("unroll")                                                            \
  for (int r = 0; r < 2; ++r) {                                                \
    int idx = r * 256 + t;                                                     \
    int srow = idx >> 2;                                                       \
    int slot = (idx & 3) ^ ((srow >> 1) & 3);                                  \
    union { u32 u[4]; s16x8 v; } aw;                                           \
    aw.u[0] = cvtpk(areg0[r][0], areg0[r][1]);                                 \
    aw.u[1] = cvtpk(areg0[r][2], areg0[r][3]);                                 \
    aw.u[2] = cvtpk(areg1[r][0], areg1[r][1]);                                 \
    aw.u[3] = cvtpk(areg1[r][2], areg1[r][3]);                                 \
    *(s16x8*)&sA[BUF][srow * 32 + slot * 8] = aw.v;                            \
  }

  f32x4 areg0[2], areg1[2];
  STAGE_B(0, 0);
  LOAD_A(0);
  WRITE_A(0);

  for (int kt = 0; kt < HID; kt += 32) {
    int cur = (kt >> 5) & 1;
    __syncthreads();
    bool more = (kt + 32) < HID;
    if (more) {
      STAGE_B(kt + 32, 1 - cur);
      LOAD_A(kt + 32);
    }
    s16x8 af[4], bfr[4];
#pragma unroll
    for (int m = 0; m < 4; ++m)
      af[m] = *(const s16x8*)&sA[cur][(wr * 64 + m * 16 + lrow) * 32 + kswz];
#pragma unroll
    for (int n = 0; n < 4; ++n)
      bfr[n] = *(const s16x8*)&sB[cur][(wc * 64 + n * 16 + lrow) * 32 + kswz];
#pragma unroll
    for (int m = 0; m < 4; ++m)
#pragma unroll
      for (int n = 0; n < 4; ++n)
        acc[m][n] = mfma16(af[m], bfr[n], acc[m][n]);
    if (more) {
      WRITE_A(1 - cur);
    }
  }
#undef STAGE_B
#undef LOAD_A
#undef WRITE_A
  mfma_fence();
  if (zz == 2) {
    // packed V-frag epilogue (R9-verified)
#pragma unroll
    for (int m = 0; m < 4; ++m)
#pragma unroll
      for (int n = 0; n < 4; ++n) {
        int rr = row0 + wr * 64 + m * 16 + lhi * 4;       // t-row of j=0
        int cc = col0 + wc * 64 + n * 16 + lrow;          // hidden col
        int bb = rr >> 11, tt = rr & 2047;
        int hh = cc >> 6, chl = cc & 63;
        size_t off = ((size_t)(bb * NH + hh)) * ((size_t)CH * S_) +
                     (size_t)(((tt >> 4) * 4 + (chl >> 4)) * 256 +
                              ((tt >> 2) & 3) * 64 + (chl & 15) * 4);
        u32 w0 = (u32)f2bf(acc[m][n][0]) | ((u32)f2bf(acc[m][n][1]) << 16);
        u32 w1 = (u32)f2bf(acc[m][n][2]) | ((u32)f2bf(acc[m][n][3]) << 16);
        uint2 w; w.x = w0; w.y = w1;
        *(uint2*)&Vfrag[off] = w;
      }
  } else {
    // z==0: fold 1/sqrt(64) AND 1/ln(2) so k_attn uses exp2 directly
    float scl = (zz == 0) ? 0.125f * 1.44269504f : 1.0f;
#pragma unroll
    for (int m = 0; m < 4; ++m)
#pragma unroll
      for (int n = 0; n < 4; ++n)
#pragma unroll
        for (int j = 0; j < 4; ++j) {
          int rr = row0 + wr * 64 + m * 16 + lhi * 4 + j;
          int cc = col0 + wc * 64 + n * 16 + lrow;
          C[(size_t)rr * HID + cc] = f2bf(acc[m][n][j] * scl);
        }
  }
}

// ---------- kernel 3: causal flash attention, KV-SPLIT bf16 partials ----------
// R19-verified (the best configuration; R20's V-from-global was a regression
// because V loads share vmcnt with K-prefetch gload_lds and their L2 latency
// lands serially in the PV chain -- V STAGING IS LOAD-BEARING).
__global__ __launch_bounds__(512) void k_attn(const u16* __restrict__ eq,
                                              const u16* __restrict__ ek,
                                              const u16* __restrict__ vf,
                                              u16* __restrict__ op0,
                                              u16* __restrict__ op1,
                                              float* __restrict__ lp) {
  int bh = blockIdx.x;                 // b*NH + h
  int b = bh >> 4, h = bh & 15;
  int yy = blockIdx.y;                 // heavy-first: qt = 15 - (yy>>1)
  int qt = 15 - (yy >> 1);
  int half = yy & 1;
  int q0b = qt * 128;
  int wave = threadIdx.x >> 6, lane = threadIdx.x & 63;
  int lrow = lane & 15, lhi = lane >> 4;
  int q0w = q0b + wave * 16;

  // flattened LDS: [0,4096) K buf0 | [4096,8192) K buf1
  //                [8192,12288) V buf0 | [12288,16384) V buf1   (u16 units)
  __shared__ __align__(16) u16 sKV[16384];

  const u16* gK = ek + (size_t)(b * S_) * HID + h * CH;
  const u16* gV = vf + (size_t)bh * ((size_t)CH * S_);

  // Q fragments (emb_q pre-scaled); swapped-QK B-frag layout.
  s16x8 qf[2];
  {
    size_t qbase = (size_t)(b * S_ + q0w + lrow) * HID + h * CH;
    qf[0] = *(const s16x8*)(eq + qbase + lhi * 8);
    qf[1] = *(const s16x8*)(eq + qbase + 32 + lhi * 8);
  }

  f32x4 o[4] = {};                 // accumulated ONLY by MFMA inside the loop
  f32x4 zreg = {0.f, 0.f, 0.f, 0.f};   // persistent SrcC zero (never rewritten)
  float lsum = 0.0f;

  // staging lane mapping (XOR-swizzled K; chunk = 8 t-rows; wave stages chunk w)
  int lr8 = lane >> 3, slot = lane & 7;
  int co = ((slot ^ lr8) << 3);    // inverse-swizzled source column (elems)

  // loop-invariant lane read bases (u16 units)
  int kb_lane = lrow * 64 + ((lhi ^ (lrow & 7)) << 3);   // K frag base (1st half)
  int vb_lane = lhi * 64 + lrow * 4;                     // V frag base

  int nst = qt + 1;                // steps in this half
  int sbase = half * nst;          // global step offset
  int tb0 = sbase * 64;

  // prologue: stage first tile of this half into buf0
  gload_lds16(gK + (size_t)(tb0 + wave * 8 + lr8) * HID + co, &sKV[wave * 512]);
  gload_lds16(gV + (size_t)(tb0 >> 4) * 1024 + wave * 512 + lane * 8,
              &sKV[8192 + wave * 512]);

#define ATTN_STEP(ST, BUF)                                                     \
  {                                                                            \
    int tb = (sbase + (ST)) * 64;                                              \
    __syncthreads();                                                           \
    if ((ST) + 1 < nst) {                                                      \
      int tb2 = tb + 64;                                                       \
      gload_lds16(gK + (size_t)(tb2 + wave * 8 + lr8) * HID + co,              \
                  &sKV[(1 - (BUF)) * 4096 + wave * 512]);                      \
      gload_lds16(gV + (size_t)(tb2 >> 4) * 1024 + wave * 512 + lane * 8,      \
                  &sKV[8192 + (1 - (BUF)) * 4096 + wave * 512]);               \
    }                                                                          \
    if (tb <= q0w + 15) {                                                      \
      f32x4 p[4];                                                              \
      _Pragma("unroll")                                                        \
      for (int kvf = 0; kvf < 4; ++kvf) {                                      \
        s16x8 k0 = *(const s16x8*)&sKV[(BUF) * 4096 + kvf * 1024 + kb_lane];   \
        s16x8 k1 = *(const s16x8*)&sKV[(BUF) * 4096 + kvf * 1024 +             \
                                       (kb_lane ^ 32)];                        \
        p[kvf] = mfma16z(k0, qf[0], zreg);                                     \
        p[kvf] = mfma16t(k1, qf[1], p[kvf]);                                   \
      }                                                                        \
      mfma_fence();                                                            \
      s16x4 pa[4];                                                             \
      if (tb + 63 > q0w) {            /* diagonal step: wave-uniform branch */ \
        _Pragma("unroll")                                                      \
        for (int kvf = 0; kvf < 4; ++kvf) {                                    \
          float e[4];                                                          \
          _Pragma("unroll")                                                    \
          for (int j = 0; j < 4; ++j) {                                        \
            float v = p[kvf][j];                                               \
            if (tb + kvf * 16 + lhi * 4 + j > q0w + lrow) v = -3.0e38f;        \
            e[j] = fexp2(v);                                                   \
          }                                                                    \
          lsum += (e[0] + e[1]) + (e[2] + e[3]);                               \
          union { u32 u[2]; s16x4 v4; } pk;                                    \
          pk.u[0] = cvtpk(e[0], e[1]);                                         \
          pk.u[1] = cvtpk(e[2], e[3]);                                         \
          pa[kvf] = pk.v4;                                                     \
        }                                                                      \
      } else {                        /* interior step: no mask VALU at all */ \
        _Pragma("unroll")                                                      \
        for (int kvf = 0; kvf < 4; ++kvf) {                                    \
          float e[4];                                                          \
          _Pragma("unroll")                                                    \
          for (int j = 0; j < 4; ++j) e[j] = fexp2(p[kvf][j]);                 \
          lsum += (e[0] + e[1]) + (e[2] + e[3]);                               \
          union { u32 u[2]; s16x4 v4; } pk;                                    \
          pk.u[0] = cvtpk(e[0], e[1]);                                         \
          pk.u[1] = cvtpk(e[2], e[3]);                                         \
          pa[kvf] = pk.v4;                                                     \
        }                                                                      \
      }                                                                        \
      asm volatile("s_nop 1" :::);  /* cvtpk(VALU) -> pa as MFMA SrcA guard */ \
      _Pragma("unroll")                                                        \
      for (int n = 0; n < 4; ++n)                                              \
        _Pragma("unroll")                                                      \
        for (int kvf = 0; kvf < 4; ++kvf) {                                    \
          s16x4 vfr = *(const s16x4*)&sKV[8192 + (BUF) * 4096 +                \
                                          (kvf * 4 + n) * 256 + vb_lane];      \
          o[n] = mfma16k16t(pa[kvf], vfr, o[n]);                               \
        }                                                                      \
    }                                                                          \
  }

  for (int st2 = 0; st2 < nst; st2 += 2) {
    ATTN_STEP(st2, 0);
    if (st2 + 1 < nst) ATTN_STEP(st2 + 1, 1);
  }
#undef ATTN_STEP

  mfma_fence();

  // reduce lsum across the 4 hi-groups: every lane ends with total for q = lrow
  lsum += __shfl_xor(lsum, 16);
  lsum += __shfl_xor(lsum, 32);

  u16* ob = half ? op1 : op0;
#pragma unroll
  for (int j = 0; j < 4; ++j) {
    int q = q0w + lhi * 4 + j;
    u16* op = ob + (size_t)(b * S_ + q) * HID + h * CH + lrow;
#pragma unroll
    for (int n = 0; n < 4; ++n)
      op[n * 16] = f2bf(o[n][j]);        // unnormalized bf16 partial
  }
  if (lhi == 0) {                        // one lane set per q-row
    int q = q0w + lrow;
    lp[(((size_t)half * B_ + b) * S_ + q) * NH + h] = lsum;
  }
}

// ---------- kernel 4: combine bf16 partials + normalize -> fp32 out ----------
__global__ __launch_bounds__(256) void k_combine(float* __restrict__ out,
                                                 const u16* __restrict__ p0,
                                                 const u16* __restrict__ p1,
                                                 const float* __restrict__ lp) {
  size_t i = ((size_t)blockIdx.x * 256 + threadIdx.x) * 8;
  size_t row = i >> 10;                  // b*S + s
  int h = (int)((i & 1023) >> 6);        // same h for all 8
  size_t b = row >> 11, s = row & 2047;
  float l0 = lp[((0 * B_ + b) * S_ + s) * NH + h];
  float l1 = lp[((1 * B_ + b) * S_ + s) * NH + h];
  float inv = 1.0f / (l0 + l1);
  uint4 a = *(const uint4*)&p0[i];
  uint4 c = *(const uint4*)&p1[i];
  f32x4 r0, r1;
  r0[0] = (bf2f((u16)(a.x & 0xFFFF)) + bf2f((u16)(c.x & 0xFFFF))) * inv;
  r0[1] = (bf2f((u16)(a.x >> 16))    + bf2f((u16)(c.x >> 16)))    * inv;
  r0[2] = (bf2f((u16)(a.y & 0xFFFF)) + bf2f((u16)(c.y & 0xFFFF))) * inv;
  r0[3] = (bf2f((u16)(a.y >> 16))    + bf2f((u16)(c.y >> 16)))    * inv;
  r1[0] = (bf2f((u16)(a.z & 0xFFFF)) + bf2f((u16)(c.z & 0xFFFF))) * inv;
  r1[1] = (bf2f((u16)(a.z >> 16))    + bf2f((u16)(c.z >> 16)))    * inv;
  r1[2] = (bf2f((u16)(a.w & 0xFFFF)) + bf2f((u16)(c.w & 0xFFFF))) * inv;
  r1[3] = (bf2f((u16)(a.w >> 16))    + bf2f((u16)(c.w >> 16)))    * inv;
  *(f32x4*)(out + i) = r0;
  *(f32x4*)(out + i + 4) = r1;
}

// ---------- launch ----------
extern "C" void kernel_launch(void* const* d_in, const int* in_sizes, int n_in,
                              void* d_out, int out_size, void* d_ws, size_t ws_size,
                              hipStream_t stream) {
  const float* q  = (const float*)d_in[0];
  const float* k  = (const float*)d_in[1];
  const float* v  = (const float*)d_in[2];
  const float* wq = (const float*)d_in[3];
  const float* wk = (const float*)d_in[4];
  const float* wv = (const float*)d_in[5];
  float* out = (float*)d_out;

  // layout: first 24MB region is scratch for partials; rest unchanged.
  u16* scratch = (u16*)d_ws;             // 3*NELEM u16 region
  u16* wT  = scratch + 3 * NELEM;        // 3 * WELEM
  u16* emb = wT + 3 * WELEM;             // 3 * NELEM (z2 slot holds V-frag)
  u16* vfr = emb + 2 * NELEM;            // packed V-frag written by k_gemm z==2

  u16* p0b = scratch;                    // NELEM bf16 = 8 MB
  u16* p1b = scratch + NELEM;            // NELEM bf16 = 8 MB
  float* lp = (float*)(scratch + 2 * NELEM);  // 2*B*S*NH fp32 = 512 KB

  k_transposeW<<<dim3(16, 16, 3), 256, 0, stream>>>(wq, wk, wv, wT);
  k_gemm<<<dim3(768), 256, 0, stream>>>(q, k, v, wT, emb, vfr);
  k_attn<<<dim3(B_ * NH, 32), 512, 0, stream>>>(emb, emb + NELEM, vfr,
                                                p0b, p1b, lp);
  k_combine<<<dim3(NELEM / (256 * 8)), 256, 0, stream>>>(out, p0b, p1b, lp);
}